// Round 1
// baseline (499.657 us; speedup 1.0000x reference)
//
#include <hip/hip_runtime.h>

#define N_NODES 100000
#define N_EDGES 1600000
#define IN_CH 8
#define N_CLASSES 16
// MAX_ORDER+1 = 2, N_RINGS = 2

// ws layout:
//   aggrRe: [N_NODES][r=2][f=8][o=2]  -> 3,200,000 floats
//   aggrIm: [N_NODES][r=2][f=8]       -> 1,600,000 floats (o=1 only; o=0 im == 0)
#define AGGR_RE_FLOATS (N_NODES * 32)
#define AGGR_IM_FLOATS (N_NODES * 16)
#define WS_FLOATS (AGGR_RE_FLOATS + AGGR_IM_FLOATS)   // 4,800,000
#define WS_F4 (WS_FLOATS / 4)                          // 1,200,000

__global__ __launch_bounds__(256) void zero_ws_kernel(float4* __restrict__ ws, int n4) {
    int i = blockIdx.x * blockDim.x + threadIdx.x;
    if (i < n4) ws[i] = make_float4(0.f, 0.f, 0.f, 0.f);
}

// 8 lanes per edge; lane handles one feature f.
__global__ __launch_bounds__(256) void edge_kernel(
    const int* __restrict__ ei,        // [2][N_EDGES]
    const float* __restrict__ x,       // [N_NODES][8]
    const float* __restrict__ precomp, // [N_EDGES][o=2][r=2][reim=2]
    float* __restrict__ aggrRe,        // [N][r][f][o]
    float* __restrict__ aggrIm)        // [N][r][f]
{
    int gid = blockIdx.x * blockDim.x + threadIdx.x;
    int e = gid >> 3;
    int f = gid & 7;
    if (e >= N_EDGES) return;

    int src = ei[e];
    int tgt = ei[N_EDGES + e];
    float xv = x[tgt * IN_CH + f];

    const float4* pc = (const float4*)(precomp + (size_t)e * 8);
    float4 p0 = pc[0];  // o=0: (r0.re, r0.im, r1.re, r1.im)
    float4 p1 = pc[1];  // o=1: (r0.re, r0.im, r1.re, r1.im)
    // pre_re[r,o]: o0r0=p0.x o0r1=p0.z o1r0=p1.x o1r1=p1.z
    // pre_im[r,o]: o=0 zeroed by signs; o1r0=p1.y o1r1=p1.w

    float* ar = aggrRe + (size_t)src * 32;   // [r][f][o]
    atomicAdd(ar + ((0 * 8 + f) * 2 + 0), xv * p0.x);
    atomicAdd(ar + ((1 * 8 + f) * 2 + 0), xv * p0.z);
    atomicAdd(ar + ((0 * 8 + f) * 2 + 1), xv * p1.x);
    atomicAdd(ar + ((1 * 8 + f) * 2 + 1), xv * p1.z);

    float* ai = aggrIm + (size_t)src * 16;   // [r][f]
    atomicAdd(ai + (0 * 8 + f), xv * p1.y);
    atomicAdd(ai + (1 * 8 + f), xv * p1.w);
}

// 16 lanes per node; lane handles one class c.
__global__ __launch_bounds__(256) void node_kernel(
    const float* __restrict__ aggrRe,  // [N][r][f][o]
    const float* __restrict__ aggrIm,  // [N][r][f]
    const float* __restrict__ prof,    // [4][2][16][8], only o=0,1 used
    const float* __restrict__ bias,    // [16]
    float* __restrict__ out)           // [N][16]
{
    __shared__ float sprof[512];  // [o=2][r=2][c=16][f=8]
    for (int i = threadIdx.x; i < 512; i += blockDim.x) sprof[i] = prof[i];
    __syncthreads();

    int gid = blockIdx.x * blockDim.x + threadIdx.x;
    int n = gid >> 4;
    int c = gid & 15;
    if (n >= N_NODES) return;

    const float* ar = aggrRe + (size_t)n * 32;
    const float* ai = aggrIm + (size_t)n * 16;

    float re0 = 0.f, re1 = 0.f, im1 = 0.f;
#pragma unroll
    for (int r = 0; r < 2; ++r) {
#pragma unroll
        for (int f = 0; f < 8; ++f) {
            float a0 = ar[(r * 8 + f) * 2 + 0];
            float a1 = ar[(r * 8 + f) * 2 + 1];
            float aI = ai[r * 8 + f];
            float w0 = sprof[(0 * 2 + r) * 128 + c * 8 + f];
            float w1 = sprof[(1 * 2 + r) * 128 + c * 8 + f];
            re0 = fmaf(w0, a0, re0);
            re1 = fmaf(w1, a1, re1);
            im1 = fmaf(w1, aI, im1);
        }
    }

    float mag = sqrtf(fmaxf(re0 * re0, 1e-12f)) +
                sqrtf(fmaxf(re1 * re1 + im1 * im1, 1e-12f));
    float logit = mag + bias[c];

    // log-softmax across the 16-lane class group
    float m = logit;
#pragma unroll
    for (int off = 1; off < 16; off <<= 1) m = fmaxf(m, __shfl_xor(m, off, 16));
    float ex = __expf(logit - m);
    float s = ex;
#pragma unroll
    for (int off = 1; off < 16; off <<= 1) s += __shfl_xor(s, off, 16);

    out[n * N_CLASSES + c] = (logit - m) - logf(s);
}

extern "C" void kernel_launch(void* const* d_in, const int* in_sizes, int n_in,
                              void* d_out, int out_size, void* d_ws, size_t ws_size,
                              hipStream_t stream) {
    const float* x       = (const float*)d_in[0];
    const int*   ei      = (const int*)d_in[1];
    const float* precomp = (const float*)d_in[2];
    // d_in[3] = connection (unused by reference)
    const float* prof    = (const float*)d_in[4];
    const float* bias    = (const float*)d_in[5];
    float* out = (float*)d_out;

    float* aggrRe = (float*)d_ws;
    float* aggrIm = aggrRe + AGGR_RE_FLOATS;

    zero_ws_kernel<<<(WS_F4 + 255) / 256, 256, 0, stream>>>((float4*)d_ws, WS_F4);

    int edge_threads = N_EDGES * 8;
    edge_kernel<<<(edge_threads + 255) / 256, 256, 0, stream>>>(ei, x, precomp, aggrRe, aggrIm);

    int node_threads = N_NODES * 16;
    node_kernel<<<(node_threads + 255) / 256, 256, 0, stream>>>(aggrRe, aggrIm, prof, bias, out);
}

// Round 2
// 460.654 us; speedup vs baseline: 1.0847x; 1.0847x over previous
//
#include <hip/hip_runtime.h>

#define N_NODES 100000
#define N_EDGES 1600000
#define IN_CH 8
#define N_CLASSES 16
// MAX_ORDER+1 = 2, N_RINGS = 2

// ---------------- CSR-path ws layout (bytes) ----------------
// cp:     float4[2*N_EDGES]   @ 0           (51,200,000 B)
// ctgt:   int[N_EDGES]        @ 51,200,000  ( 6,400,000 B)
// off:    int[N_NODES+1]      @ 57,600,000  (   400,004 B)
// cursor: int[N_NODES]        @ 58,000,016  (   400,000 B)
#define CP_OFF      0
#define CTGT_OFF    (2ull * N_EDGES * 16ull)
#define OFF_OFF     (CTGT_OFF + (size_t)N_EDGES * 4)
#define CURSOR_OFF  (OFF_OFF + ((size_t)N_NODES + 4) * 4)
#define CSR_WS_BYTES (CURSOR_OFF + (size_t)N_NODES * 4)

// ---------------- fallback (atomic) ws layout ----------------
#define AGGR_RE_FLOATS (N_NODES * 32)
#define AGGR_IM_FLOATS (N_NODES * 16)
#define WS_FLOATS (AGGR_RE_FLOATS + AGGR_IM_FLOATS)
#define WS_F4 (WS_FLOATS / 4)

// ======================= CSR path =======================

__global__ __launch_bounds__(256) void zero_deg_kernel(int* __restrict__ deg) {
    int i = blockIdx.x * blockDim.x + threadIdx.x;
    if (i < N_NODES) deg[i] = 0;
}

__global__ __launch_bounds__(256) void count_kernel(const int* __restrict__ ei,
                                                    int* __restrict__ deg) {
    int e = blockIdx.x * blockDim.x + threadIdx.x;
    if (e < N_EDGES) atomicAdd(&deg[ei[e]], 1);
}

// single-block exclusive scan: off[n], off[N]=total, cursor[n]=off[n]
__global__ __launch_bounds__(1024) void scan_kernel(const int* __restrict__ deg,
                                                    int* __restrict__ off,
                                                    int* __restrict__ cursor) {
    __shared__ int part[1024];
    const int T = 1024;
    int t = threadIdx.x;
    const int chunk = (N_NODES + T - 1) / T;  // 98
    int lo = t * chunk;
    int hi = lo + chunk; if (hi > N_NODES) hi = N_NODES;
    int s = 0;
    for (int i = lo; i < hi; ++i) s += deg[i];
    part[t] = s;
    __syncthreads();
    for (int d = 1; d < T; d <<= 1) {
        int v = (t >= d) ? part[t - d] : 0;
        __syncthreads();
        part[t] += v;
        __syncthreads();
    }
    int run = (t == 0) ? 0 : part[t - 1];
    for (int i = lo; i < hi; ++i) {
        off[i] = run; cursor[i] = run;
        run += deg[i];
    }
    if (t == T - 1) off[N_NODES] = run;
}

__global__ __launch_bounds__(256) void scatter_kernel(
    const int* __restrict__ ei, const float* __restrict__ precomp,
    int* __restrict__ cursor, int* __restrict__ ctgt, float4* __restrict__ cp) {
    int e = blockIdx.x * blockDim.x + threadIdx.x;
    if (e >= N_EDGES) return;
    int src = ei[e];
    int tgt = ei[N_EDGES + e];
    int pos = atomicAdd(&cursor[src], 1);
    const float4* pc = (const float4*)(precomp + (size_t)e * 8);
    float4 p0 = pc[0], p1 = pc[1];
    ctgt[pos] = tgt;
    cp[2 * pos]     = p0;
    cp[2 * pos + 1] = p1;
}

// 16 nodes/block, 16 lanes/node. Phase 1: lane=(r,f) accumulates over CSR edges.
// Phase 2: lane=class, einsum + magnitude + log-softmax.
__global__ __launch_bounds__(256) void gather_node_kernel(
    const int* __restrict__ off, const int* __restrict__ ctgt,
    const float4* __restrict__ cp, const float* __restrict__ x,
    const float* __restrict__ prof, const float* __restrict__ bias,
    float* __restrict__ out) {
    __shared__ float sprof[512];       // [o=2][r=2][c=16][f=8]
    __shared__ float acc[16][49];      // 48 accums per node, padded
    for (int i = threadIdx.x; i < 512; i += 256) sprof[i] = prof[i];
    __syncthreads();

    int sn = threadIdx.x >> 4;
    int l = threadIdx.x & 15;
    int nid = blockIdx.x * 16 + sn;    // N_NODES = 6250*16 exactly, no tail
    int r = l >> 3, f = l & 7;

    float a0 = 0.f, a1 = 0.f, aI = 0.f;
    int lo = off[nid], hi = off[nid + 1];
    for (int j = lo; j < hi; ++j) {
        int tgt = ctgt[j];
        float4 q0 = cp[2 * j];
        float4 q1 = cp[2 * j + 1];
        float xv = x[tgt * IN_CH + f];
        float p0  = r ? q0.z : q0.x;
        float p1r = r ? q1.z : q1.x;
        float p1i = r ? q1.w : q1.y;
        a0 = fmaf(xv, p0, a0);
        a1 = fmaf(xv, p1r, a1);
        aI = fmaf(xv, p1i, aI);
    }
    acc[sn][l * 3 + 0] = a0;
    acc[sn][l * 3 + 1] = a1;
    acc[sn][l * 3 + 2] = aI;
    __syncthreads();

    int c = l;
    float re0 = 0.f, re1 = 0.f, im1 = 0.f;
#pragma unroll
    for (int rr = 0; rr < 2; ++rr) {
#pragma unroll
        for (int ff = 0; ff < 8; ++ff) {
            int rf = rr * 8 + ff;
            float v0 = acc[sn][rf * 3 + 0];
            float v1 = acc[sn][rf * 3 + 1];
            float vI = acc[sn][rf * 3 + 2];
            float w0 = sprof[(0 * 2 + rr) * 128 + c * 8 + ff];
            float w1 = sprof[(1 * 2 + rr) * 128 + c * 8 + ff];
            re0 = fmaf(w0, v0, re0);
            re1 = fmaf(w1, v1, re1);
            im1 = fmaf(w1, vI, im1);
        }
    }
    float mag = sqrtf(fmaxf(re0 * re0, 1e-12f)) +
                sqrtf(fmaxf(re1 * re1 + im1 * im1, 1e-12f));
    float logit = mag + bias[c];

    float m = logit;
#pragma unroll
    for (int o = 1; o < 16; o <<= 1) m = fmaxf(m, __shfl_xor(m, o, 16));
    float ex = __expf(logit - m);
    float s = ex;
#pragma unroll
    for (int o = 1; o < 16; o <<= 1) s += __shfl_xor(s, o, 16);

    out[nid * N_CLASSES + c] = (logit - m) - logf(s);
}

// ======================= fallback (R1 atomic path) =======================

__global__ __launch_bounds__(256) void zero_ws_kernel(float4* __restrict__ ws, int n4) {
    int i = blockIdx.x * blockDim.x + threadIdx.x;
    if (i < n4) ws[i] = make_float4(0.f, 0.f, 0.f, 0.f);
}

__global__ __launch_bounds__(256) void edge_kernel(
    const int* __restrict__ ei, const float* __restrict__ x,
    const float* __restrict__ precomp,
    float* __restrict__ aggrRe, float* __restrict__ aggrIm) {
    int gid = blockIdx.x * blockDim.x + threadIdx.x;
    int e = gid >> 3;
    int f = gid & 7;
    if (e >= N_EDGES) return;
    int src = ei[e];
    int tgt = ei[N_EDGES + e];
    float xv = x[tgt * IN_CH + f];
    const float4* pc = (const float4*)(precomp + (size_t)e * 8);
    float4 p0 = pc[0], p1 = pc[1];
    float* ar = aggrRe + (size_t)src * 32;
    atomicAdd(ar + ((0 * 8 + f) * 2 + 0), xv * p0.x);
    atomicAdd(ar + ((1 * 8 + f) * 2 + 0), xv * p0.z);
    atomicAdd(ar + ((0 * 8 + f) * 2 + 1), xv * p1.x);
    atomicAdd(ar + ((1 * 8 + f) * 2 + 1), xv * p1.z);
    float* ai = aggrIm + (size_t)src * 16;
    atomicAdd(ai + (0 * 8 + f), xv * p1.y);
    atomicAdd(ai + (1 * 8 + f), xv * p1.w);
}

__global__ __launch_bounds__(256) void node_kernel(
    const float* __restrict__ aggrRe, const float* __restrict__ aggrIm,
    const float* __restrict__ prof, const float* __restrict__ bias,
    float* __restrict__ out) {
    __shared__ float sprof[512];
    for (int i = threadIdx.x; i < 512; i += blockDim.x) sprof[i] = prof[i];
    __syncthreads();
    int gid = blockIdx.x * blockDim.x + threadIdx.x;
    int n = gid >> 4;
    int c = gid & 15;
    if (n >= N_NODES) return;
    const float* ar = aggrRe + (size_t)n * 32;
    const float* ai = aggrIm + (size_t)n * 16;
    float re0 = 0.f, re1 = 0.f, im1 = 0.f;
#pragma unroll
    for (int r = 0; r < 2; ++r)
#pragma unroll
        for (int f = 0; f < 8; ++f) {
            float a0 = ar[(r * 8 + f) * 2 + 0];
            float a1 = ar[(r * 8 + f) * 2 + 1];
            float aI = ai[r * 8 + f];
            float w0 = sprof[(0 * 2 + r) * 128 + c * 8 + f];
            float w1 = sprof[(1 * 2 + r) * 128 + c * 8 + f];
            re0 = fmaf(w0, a0, re0);
            re1 = fmaf(w1, a1, re1);
            im1 = fmaf(w1, aI, im1);
        }
    float mag = sqrtf(fmaxf(re0 * re0, 1e-12f)) +
                sqrtf(fmaxf(re1 * re1 + im1 * im1, 1e-12f));
    float logit = mag + bias[c];
    float m = logit;
#pragma unroll
    for (int o = 1; o < 16; o <<= 1) m = fmaxf(m, __shfl_xor(m, o, 16));
    float ex = __expf(logit - m);
    float s = ex;
#pragma unroll
    for (int o = 1; o < 16; o <<= 1) s += __shfl_xor(s, o, 16);
    out[n * N_CLASSES + c] = (logit - m) - logf(s);
}

// ======================= launch =======================

extern "C" void kernel_launch(void* const* d_in, const int* in_sizes, int n_in,
                              void* d_out, int out_size, void* d_ws, size_t ws_size,
                              hipStream_t stream) {
    const float* x       = (const float*)d_in[0];
    const int*   ei      = (const int*)d_in[1];
    const float* precomp = (const float*)d_in[2];
    const float* prof    = (const float*)d_in[4];
    const float* bias    = (const float*)d_in[5];
    float* out = (float*)d_out;

    if (ws_size >= CSR_WS_BYTES) {
        char* ws = (char*)d_ws;
        float4* cp   = (float4*)(ws + CP_OFF);
        int* ctgt    = (int*)(ws + CTGT_OFF);
        int* off     = (int*)(ws + OFF_OFF);
        int* cursor  = (int*)(ws + CURSOR_OFF);

        zero_deg_kernel<<<(N_NODES + 255) / 256, 256, 0, stream>>>(cursor);
        count_kernel<<<(N_EDGES + 255) / 256, 256, 0, stream>>>(ei, cursor);
        scan_kernel<<<1, 1024, 0, stream>>>(cursor, off, cursor);
        scatter_kernel<<<(N_EDGES + 255) / 256, 256, 0, stream>>>(ei, precomp, cursor, ctgt, cp);
        gather_node_kernel<<<N_NODES / 16, 256, 0, stream>>>(off, ctgt, cp, x, prof, bias, out);
    } else {
        float* aggrRe = (float*)d_ws;
        float* aggrIm = aggrRe + AGGR_RE_FLOATS;
        zero_ws_kernel<<<(WS_F4 + 255) / 256, 256, 0, stream>>>((float4*)d_ws, WS_F4);
        int edge_threads = N_EDGES * 8;
        edge_kernel<<<(edge_threads + 255) / 256, 256, 0, stream>>>(ei, x, precomp, aggrRe, aggrIm);
        int node_threads = N_NODES * 16;
        node_kernel<<<(node_threads + 255) / 256, 256, 0, stream>>>(aggrRe, aggrIm, prof, bias, out);
    }
}

// Round 3
// 238.579 us; speedup vs baseline: 2.0943x; 1.9308x over previous
//
#include <hip/hip_runtime.h>

#define N_NODES 100000
#define N_EDGES 1600000
#define IN_CH 8
#define N_CLASSES 16
// MAX_ORDER+1 = 2, N_RINGS = 2

#define SCAN_BLK 1024
#define N_SCAN_BLOCKS ((N_NODES + SCAN_BLK - 1) / SCAN_BLK)   // 98

// ---------------- CSR-path ws layout (bytes) ----------------
// cp:        float4[2*N_EDGES]      @ 0
// ctgt:      int[N_EDGES]
// off:       int[N_NODES+1]
// cursor:    int[N_NODES]
// blockSums: int[N_SCAN_BLOCKS]
// blockOff:  int[N_SCAN_BLOCKS]
#define CP_OFF      0
#define CTGT_OFF    (2ull * N_EDGES * 16ull)
#define OFF_OFF     (CTGT_OFF + (size_t)N_EDGES * 4)
#define CURSOR_OFF  (OFF_OFF + ((size_t)N_NODES + 4) * 4)
#define BSUM_OFF    (CURSOR_OFF + (size_t)N_NODES * 4)
#define BOFF_OFF    (BSUM_OFF + (size_t)N_SCAN_BLOCKS * 4)
#define CSR_WS_BYTES (BOFF_OFF + (size_t)N_SCAN_BLOCKS * 4)

// ---------------- fallback (atomic) ws layout ----------------
#define AGGR_RE_FLOATS (N_NODES * 32)
#define AGGR_IM_FLOATS (N_NODES * 16)
#define WS_FLOATS (AGGR_RE_FLOATS + AGGR_IM_FLOATS)
#define WS_F4 (WS_FLOATS / 4)

// ======================= CSR path =======================

__global__ __launch_bounds__(256) void zero_deg_kernel(int* __restrict__ deg) {
    int i = blockIdx.x * blockDim.x + threadIdx.x;
    if (i < N_NODES) deg[i] = 0;
}

__global__ __launch_bounds__(256) void count_kernel(const int* __restrict__ ei,
                                                    int* __restrict__ deg) {
    int e = blockIdx.x * blockDim.x + threadIdx.x;
    if (e < N_EDGES) atomicAdd(&deg[ei[e]], 1);
}

// per-block reduce of deg -> blockSums
__global__ __launch_bounds__(SCAN_BLK) void scan1_kernel(const int* __restrict__ deg,
                                                         int* __restrict__ blockSums) {
    __shared__ int buf[SCAN_BLK];
    int t = threadIdx.x;
    int i = blockIdx.x * SCAN_BLK + t;
    buf[t] = (i < N_NODES) ? deg[i] : 0;
    __syncthreads();
#pragma unroll
    for (int d = SCAN_BLK / 2; d > 0; d >>= 1) {
        if (t < d) buf[t] += buf[t + d];
        __syncthreads();
    }
    if (t == 0) blockSums[blockIdx.x] = buf[0];
}

// single tiny block: exclusive scan of blockSums -> blockOff
__global__ __launch_bounds__(128) void scan2_kernel(const int* __restrict__ blockSums,
                                                    int* __restrict__ blockOff) {
    __shared__ int buf[128];
    int t = threadIdx.x;
    int v = (t < N_SCAN_BLOCKS) ? blockSums[t] : 0;
    buf[t] = v;
    __syncthreads();
#pragma unroll
    for (int d = 1; d < 128; d <<= 1) {
        int u = (t >= d) ? buf[t - d] : 0;
        __syncthreads();
        buf[t] += u;
        __syncthreads();
    }
    if (t < N_SCAN_BLOCKS) blockOff[t] = buf[t] - v;   // exclusive
}

// block-local exclusive scan of deg slice + blockOff -> off, cursor; off[N]=total
__global__ __launch_bounds__(SCAN_BLK) void scan3_kernel(const int* __restrict__ deg,
                                                         const int* __restrict__ blockOff,
                                                         const int* __restrict__ blockSums,
                                                         int* __restrict__ off,
                                                         int* __restrict__ cursor) {
    __shared__ int buf[SCAN_BLK];
    int t = threadIdx.x;
    int b = blockIdx.x;
    int i = b * SCAN_BLK + t;
    int v = (i < N_NODES) ? deg[i] : 0;
    buf[t] = v;
    __syncthreads();
#pragma unroll
    for (int d = 1; d < SCAN_BLK; d <<= 1) {
        int u = (t >= d) ? buf[t - d] : 0;
        __syncthreads();
        buf[t] += u;
        __syncthreads();
    }
    if (i < N_NODES) {
        int e = blockOff[b] + buf[t] - v;   // exclusive + base
        off[i] = e;
        cursor[i] = e;
    }
    if (b == N_SCAN_BLOCKS - 1 && t == 0)
        off[N_NODES] = blockOff[b] + blockSums[b];
}

__global__ __launch_bounds__(256) void scatter_kernel(
    const int* __restrict__ ei, const float* __restrict__ precomp,
    int* __restrict__ cursor, int* __restrict__ ctgt, float4* __restrict__ cp) {
    int e = blockIdx.x * blockDim.x + threadIdx.x;
    if (e >= N_EDGES) return;
    int src = ei[e];
    int tgt = ei[N_EDGES + e];
    int pos = atomicAdd(&cursor[src], 1);
    const float4* pc = (const float4*)(precomp + (size_t)e * 8);
    float4 p0 = pc[0], p1 = pc[1];
    ctgt[pos] = tgt;
    cp[2 * pos]     = p0;
    cp[2 * pos + 1] = p1;
}

// 16 nodes/block, 16 lanes/node. Phase 1: lane=(r,f) accumulates over CSR edges.
// Phase 2: lane=class, einsum + magnitude + log-softmax.
__global__ __launch_bounds__(256) void gather_node_kernel(
    const int* __restrict__ off, const int* __restrict__ ctgt,
    const float4* __restrict__ cp, const float* __restrict__ x,
    const float* __restrict__ prof, const float* __restrict__ bias,
    float* __restrict__ out) {
    __shared__ float sprof[512];       // [o=2][r=2][c=16][f=8]
    __shared__ float acc[16][49];      // 48 accums per node, padded
    for (int i = threadIdx.x; i < 512; i += 256) sprof[i] = prof[i];
    __syncthreads();

    int sn = threadIdx.x >> 4;
    int l = threadIdx.x & 15;
    int nid = blockIdx.x * 16 + sn;    // N_NODES = 6250*16 exactly, no tail
    int r = l >> 3, f = l & 7;

    float a0 = 0.f, a1 = 0.f, aI = 0.f;
    int lo = off[nid], hi = off[nid + 1];
    for (int j = lo; j < hi; ++j) {
        int tgt = ctgt[j];
        float4 q0 = cp[2 * j];
        float4 q1 = cp[2 * j + 1];
        float xv = x[tgt * IN_CH + f];
        float p0  = r ? q0.z : q0.x;
        float p1r = r ? q1.z : q1.x;
        float p1i = r ? q1.w : q1.y;
        a0 = fmaf(xv, p0, a0);
        a1 = fmaf(xv, p1r, a1);
        aI = fmaf(xv, p1i, aI);
    }
    acc[sn][l * 3 + 0] = a0;
    acc[sn][l * 3 + 1] = a1;
    acc[sn][l * 3 + 2] = aI;
    __syncthreads();

    int c = l;
    float re0 = 0.f, re1 = 0.f, im1 = 0.f;
#pragma unroll
    for (int rr = 0; rr < 2; ++rr) {
#pragma unroll
        for (int ff = 0; ff < 8; ++ff) {
            int rf = rr * 8 + ff;
            float v0 = acc[sn][rf * 3 + 0];
            float v1 = acc[sn][rf * 3 + 1];
            float vI = acc[sn][rf * 3 + 2];
            float w0 = sprof[(0 * 2 + rr) * 128 + c * 8 + ff];
            float w1 = sprof[(1 * 2 + rr) * 128 + c * 8 + ff];
            re0 = fmaf(w0, v0, re0);
            re1 = fmaf(w1, v1, re1);
            im1 = fmaf(w1, vI, im1);
        }
    }
    float mag = sqrtf(fmaxf(re0 * re0, 1e-12f)) +
                sqrtf(fmaxf(re1 * re1 + im1 * im1, 1e-12f));
    float logit = mag + bias[c];

    float m = logit;
#pragma unroll
    for (int o = 1; o < 16; o <<= 1) m = fmaxf(m, __shfl_xor(m, o, 16));
    float ex = __expf(logit - m);
    float s = ex;
#pragma unroll
    for (int o = 1; o < 16; o <<= 1) s += __shfl_xor(s, o, 16);

    out[nid * N_CLASSES + c] = (logit - m) - logf(s);
}

// ======================= fallback (R1 atomic path) =======================

__global__ __launch_bounds__(256) void zero_ws_kernel(float4* __restrict__ ws, int n4) {
    int i = blockIdx.x * blockDim.x + threadIdx.x;
    if (i < n4) ws[i] = make_float4(0.f, 0.f, 0.f, 0.f);
}

__global__ __launch_bounds__(256) void edge_kernel(
    const int* __restrict__ ei, const float* __restrict__ x,
    const float* __restrict__ precomp,
    float* __restrict__ aggrRe, float* __restrict__ aggrIm) {
    int gid = blockIdx.x * blockDim.x + threadIdx.x;
    int e = gid >> 3;
    int f = gid & 7;
    if (e >= N_EDGES) return;
    int src = ei[e];
    int tgt = ei[N_EDGES + e];
    float xv = x[tgt * IN_CH + f];
    const float4* pc = (const float4*)(precomp + (size_t)e * 8);
    float4 p0 = pc[0], p1 = pc[1];
    float* ar = aggrRe + (size_t)src * 32;
    atomicAdd(ar + ((0 * 8 + f) * 2 + 0), xv * p0.x);
    atomicAdd(ar + ((1 * 8 + f) * 2 + 0), xv * p0.z);
    atomicAdd(ar + ((0 * 8 + f) * 2 + 1), xv * p1.x);
    atomicAdd(ar + ((1 * 8 + f) * 2 + 1), xv * p1.z);
    float* ai = aggrIm + (size_t)src * 16;
    atomicAdd(ai + (0 * 8 + f), xv * p1.y);
    atomicAdd(ai + (1 * 8 + f), xv * p1.w);
}

__global__ __launch_bounds__(256) void node_kernel(
    const float* __restrict__ aggrRe, const float* __restrict__ aggrIm,
    const float* __restrict__ prof, const float* __restrict__ bias,
    float* __restrict__ out) {
    __shared__ float sprof[512];
    for (int i = threadIdx.x; i < 512; i += blockDim.x) sprof[i] = prof[i];
    __syncthreads();
    int gid = blockIdx.x * blockDim.x + threadIdx.x;
    int n = gid >> 4;
    int c = gid & 15;
    if (n >= N_NODES) return;
    const float* ar = aggrRe + (size_t)n * 32;
    const float* ai = aggrIm + (size_t)n * 16;
    float re0 = 0.f, re1 = 0.f, im1 = 0.f;
#pragma unroll
    for (int r = 0; r < 2; ++r)
#pragma unroll
        for (int f = 0; f < 8; ++f) {
            float a0 = ar[(r * 8 + f) * 2 + 0];
            float a1 = ar[(r * 8 + f) * 2 + 1];
            float aI = ai[r * 8 + f];
            float w0 = sprof[(0 * 2 + r) * 128 + c * 8 + f];
            float w1 = sprof[(1 * 2 + r) * 128 + c * 8 + f];
            re0 = fmaf(w0, a0, re0);
            re1 = fmaf(w1, a1, re1);
            im1 = fmaf(w1, aI, im1);
        }
    float mag = sqrtf(fmaxf(re0 * re0, 1e-12f)) +
                sqrtf(fmaxf(re1 * re1 + im1 * im1, 1e-12f));
    float logit = mag + bias[c];
    float m = logit;
#pragma unroll
    for (int o = 1; o < 16; o <<= 1) m = fmaxf(m, __shfl_xor(m, o, 16));
    float ex = __expf(logit - m);
    float s = ex;
#pragma unroll
    for (int o = 1; o < 16; o <<= 1) s += __shfl_xor(s, o, 16);
    out[n * N_CLASSES + c] = (logit - m) - logf(s);
}

// ======================= launch =======================

extern "C" void kernel_launch(void* const* d_in, const int* in_sizes, int n_in,
                              void* d_out, int out_size, void* d_ws, size_t ws_size,
                              hipStream_t stream) {
    const float* x       = (const float*)d_in[0];
    const int*   ei      = (const int*)d_in[1];
    const float* precomp = (const float*)d_in[2];
    const float* prof    = (const float*)d_in[4];
    const float* bias    = (const float*)d_in[5];
    float* out = (float*)d_out;

    if (ws_size >= CSR_WS_BYTES) {
        char* ws = (char*)d_ws;
        float4* cp     = (float4*)(ws + CP_OFF);
        int* ctgt      = (int*)(ws + CTGT_OFF);
        int* off       = (int*)(ws + OFF_OFF);
        int* cursor    = (int*)(ws + CURSOR_OFF);
        int* blockSums = (int*)(ws + BSUM_OFF);
        int* blockOff  = (int*)(ws + BOFF_OFF);

        zero_deg_kernel<<<(N_NODES + 255) / 256, 256, 0, stream>>>(cursor);
        count_kernel<<<(N_EDGES + 255) / 256, 256, 0, stream>>>(ei, cursor);
        scan1_kernel<<<N_SCAN_BLOCKS, SCAN_BLK, 0, stream>>>(cursor, blockSums);
        scan2_kernel<<<1, 128, 0, stream>>>(blockSums, blockOff);
        scan3_kernel<<<N_SCAN_BLOCKS, SCAN_BLK, 0, stream>>>(cursor, blockOff, blockSums, off, cursor);
        scatter_kernel<<<(N_EDGES + 255) / 256, 256, 0, stream>>>(ei, precomp, cursor, ctgt, cp);
        gather_node_kernel<<<N_NODES / 16, 256, 0, stream>>>(off, ctgt, cp, x, prof, bias, out);
    } else {
        float* aggrRe = (float*)d_ws;
        float* aggrIm = aggrRe + AGGR_RE_FLOATS;
        zero_ws_kernel<<<(WS_F4 + 255) / 256, 256, 0, stream>>>((float4*)d_ws, WS_F4);
        int edge_threads = N_EDGES * 8;
        edge_kernel<<<(edge_threads + 255) / 256, 256, 0, stream>>>(ei, x, precomp, aggrRe, aggrIm);
        int node_threads = N_NODES * 16;
        node_kernel<<<(node_threads + 255) / 256, 256, 0, stream>>>(aggrRe, aggrIm, prof, bias, out);
    }
}